// Round 15
// baseline (203.714 us; speedup 1.0000x reference)
//
#include <hip/hip_runtime.h>
#include <hip/hip_bf16.h>

typedef unsigned short u16;
typedef unsigned int   u32;
typedef unsigned long long u64;
typedef __attribute__((ext_vector_type(8))) short bf16x8;
typedef __attribute__((ext_vector_type(4))) float f32x4;
typedef __attribute__((ext_vector_type(16))) float f32x16;

#define MFMA16(a,b,c) __builtin_amdgcn_mfma_f32_16x16x32_bf16((a),(b),(c),0,0,0)
#define MFMA32(a,b,c) __builtin_amdgcn_mfma_f32_32x32x16_bf16((a),(b),(c),0,0,0)

#define GLD16(gp, lp) __builtin_amdgcn_global_load_lds( \
    (const __attribute__((address_space(1))) void*)(gp), \
    (__attribute__((address_space(3))) void*)(lp), 16, 0, 0)

__device__ inline u32 pkbf(float a, float b) {
  __hip_bfloat16 ha = __float2bfloat16(a), hb = __float2bfloat16(b);
  return (u32)(*(u16*)&ha) | ((u32)(*(u16*)&hb) << 16);
}
__device__ inline float b2f(u16 x) {
  __hip_bfloat16 h; *(u16*)&h = x; return __bfloat162float(h);
}
// fast bf16 pair pack: round (+0x8000) then byte-perm the two high halves
__device__ inline u32 pk2(float a, float b) {
  u32 ua = __builtin_bit_cast(u32, a) + 0x8000u;
  u32 ub = __builtin_bit_cast(u32, b) + 0x8000u;
  return __builtin_amdgcn_perm(ub, ua, 0x07060302u);
}
__device__ inline float fmax3(float a, float b, float c) {
  return fmaxf(fmaxf(a, b), c);
}

// ---------------------------------------------------------------- fused casts
__global__ __launch_bounds__(256) void cast_all(const float* __restrict__ x,
                                                const float* __restrict__ wq,
                                                const float* __restrict__ wk,
                                                const float* __restrict__ wv,
                                                const float* __restrict__ wo,
                                                u16* __restrict__ xb,
                                                u16* __restrict__ wqkv,
                                                u16* __restrict__ wob) {
  int i = blockIdx.x * 256 + threadIdx.x;
  const float* src; u16* dst; int off;
  if (i < 2097152)      { src = x;  dst = xb;                 off = 0; }
  else if (i < 3145728) { src = wq; dst = wqkv;               off = 2097152; }
  else if (i < 3407872) { src = wk; dst = wqkv + 4194304;     off = 3145728; }
  else if (i < 3670016) { src = wv; dst = wqkv + 5242880;     off = 3407872; }
  else                  { src = wo; dst = wob;                off = 3670016; }
  const int k = i - off;
  float4 v = reinterpret_cast<const float4*>(src)[k];
  uint2 pk; pk.x = pkbf(v.x, v.y); pk.y = pkbf(v.z, v.w);
  reinterpret_cast<uint2*>(dst)[k] = pk;
}

__device__ inline void cstore(u16* C, size_t i, float v) {
  __hip_bfloat16 h = __float2bfloat16(v); C[i] = *(u16*)&h;
}
__device__ inline void cstore(float* C, size_t i, float v) { C[i] = v; }

// ---------------------------------------------------------------- 256x256 2-phase GEMM
// C = A * B^T, 256^2 tile, BK=32, 512 thr = 8 waves (2M x 4N), per-wave
// 128x64 (acc[8][4] = 128 VGPR). 64 KiB LDS dbuf. Per tile TWO phases, each:
//   vmcnt(counted) -> s_barrier -> ds_read (8 or 4 b128; bfr reused) ->
//   issue 2 stage-GLDs -> lgkmcnt(0)+sched_barrier -> setprio + 16 MFMA.
// Stage units are NEED-aligned: U_A0 = A rows {0-63,128-191} (fm0-3 rows for
// both wr), U_A1 = complement, U_B0/U_B1 = B row halves. Stage order per tile
// x for x+1: ph0 {A0,B0}, ph1 {B1,A1}. Steady-state waits: ph0 vmcnt(1)
// (leaves A1 of this tile + nothing), ph1 vmcnt(2). Never a full drain.
// Swizzle (proven 0-conflict): cl = (t&3) ^ ((t>>3)&3) both sides.
template<typename OutT>
__global__ __launch_bounds__(512) void gemm_2ph(const u16* __restrict__ A,
                                                const u16* __restrict__ B,
                                                OutT* __restrict__ C,
                                                int M, int N, int K) {
  __shared__ u16 SM[32768];   // 64 KB: buf 16384 u16 x2; within buf: A 8192 | B 8192
  const int t = threadIdx.x;
  const int lane = t & 63, wid = t >> 6;
  const int l15 = lane & 15, l4 = lane >> 4;
  const int wr = wid >> 2, wc = wid & 3;

  const int nwg = gridDim.x * gridDim.y;     // % 8 == 0
  int lid = blockIdx.y * gridDim.x + blockIdx.x;
  lid = (lid & 7) * (nwg >> 3) + (lid >> 3);
  const int m0 = (lid / gridDim.x) * 256, n0 = (lid % gridDim.x) * 256;

  // staging geometry: 512 slots/unit, 1 GLD/thread/unit
  const int s_r  = t >> 2;                   // 0..127 (row-in-unit)
  const int s_c  = t & 3;                    // phys chunk
  const int s_cl = s_c ^ ((t >> 3) & 3);     // logical chunk (involution)
  const int growa0 = ((s_r >> 6) << 7) + (s_r & 63);   // A unit q=0 global row
  const u16* AgU = A + (size_t)(m0 + growa0) * K + s_cl * 8;   // +q*64*K for q=1
  const u16* BgU = B + (size_t)(n0 + s_r) * K + s_cl * 8;      // +h*128*K for h=1
  const int dA = growa0 * 32 + s_c * 8;      // LDS dest (u16) within A region
  const int dB = 8192 + s_r * 32 + s_c * 8;  // within buf, B region (+h*4096)

#define STG_A(x_, q_) GLD16(AgU + (size_t)(q_) * 64 * K + (x_) * 32,           \
                            &SM[(((x_) & 1) << 14) + dA + (q_) * 64 * 32])
#define STG_B(x_, h_) GLD16(BgU + (size_t)(h_) * 128 * K + (x_) * 32,          \
                            &SM[(((x_) & 1) << 14) + dB + (h_) * 128 * 32])

  const int aph = (l4 ^ ((l15 >> 1) & 3)) * 8;   // read-side phys chunk offset
  const int arow = wr * 128 + l15;               // + (q*4+i)*16
  const int brow = wc * 64 + l15;                // + i*16

  f32x4 acc[8][4] = {};
  const int nk = K >> 5;

  // prologue: tile 0 units in consumption order A0,B0,B1,A1
  STG_A(0, 0); STG_B(0, 0); STG_B(0, 1); STG_A(0, 1);

  for (int x = 0; x < nk; ++x) {
    const int bb = (x & 1) << 14;
    const bool pre = (x + 1 < nk);

    // ---- phase 0: fm 0-3, needs U_A0, U_B0, U_B1 (oldest 3 of 4)
    asm volatile("s_waitcnt vmcnt(1)" ::: "memory");
    __builtin_amdgcn_s_barrier();
    bf16x8 af[4], bfr[4];
#pragma unroll
    for (int i = 0; i < 4; ++i)
      af[i] = *(const bf16x8*)&SM[bb + (arow + i * 16) * 32 + aph];
#pragma unroll
    for (int i = 0; i < 4; ++i)
      bfr[i] = *(const bf16x8*)&SM[bb + 8192 + (brow + i * 16) * 32 + aph];
    if (pre) { STG_A(x + 1, 0); STG_B(x + 1, 0); }
    asm volatile("s_waitcnt lgkmcnt(0)" ::: "memory");
    __builtin_amdgcn_sched_barrier(0);
    __builtin_amdgcn_s_setprio(1);
#pragma unroll
    for (int mi = 0; mi < 4; ++mi)
#pragma unroll
      for (int ni = 0; ni < 4; ++ni)
        acc[mi][ni] = MFMA16(af[mi], bfr[ni], acc[mi][ni]);
    __builtin_amdgcn_s_setprio(0);

    // ---- phase 1: fm 4-7, needs U_A1 (bfr regs reused)
    if (pre) asm volatile("s_waitcnt vmcnt(2)" ::: "memory");
    else     asm volatile("s_waitcnt vmcnt(0)" ::: "memory");
    __builtin_amdgcn_s_barrier();
#pragma unroll
    for (int i = 0; i < 4; ++i)
      af[i] = *(const bf16x8*)&SM[bb + (arow + 64 + i * 16) * 32 + aph];
    if (pre) { STG_B(x + 1, 1); STG_A(x + 1, 1); }
    asm volatile("s_waitcnt lgkmcnt(0)" ::: "memory");
    __builtin_amdgcn_sched_barrier(0);
    __builtin_amdgcn_s_setprio(1);
#pragma unroll
    for (int mi = 0; mi < 4; ++mi)
#pragma unroll
      for (int ni = 0; ni < 4; ++ni)
        acc[4 + mi][ni] = MFMA16(af[mi], bfr[ni], acc[4 + mi][ni]);
    __builtin_amdgcn_s_setprio(0);
  }

  const int crow = m0 + wr * 128 + (l4 << 2);
  const int ccol = n0 + wc * 64 + l15;
#pragma unroll
  for (int mi = 0; mi < 8; ++mi)
#pragma unroll
    for (int ni = 0; ni < 4; ++ni)
#pragma unroll
      for (int r = 0; r < 4; ++r)
        cstore(C, (size_t)(crow + mi * 16 + r) * N + (ccol + ni * 16), acc[mi][ni][r]);
#undef STG_A
#undef STG_B
}

// ---------------------------------------------------------------- small GEMM (128x128)
// Output projection: grid 16x32 = 512 blocks. Counted-vmcnt pipeline.
template<typename OutT>
__global__ __launch_bounds__(256, 4) void gemm_sm(const u16* __restrict__ A,
                                                  const u16* __restrict__ B,
                                                  OutT* __restrict__ C,
                                                  int M, int N, int K) {
  __shared__ u16 As[2][128 * 32];   // 16K
  __shared__ u16 Bs[2][128 * 32];   // 16K

  const int t = threadIdx.x;
  const int lane = t & 63, wid = t >> 6;
  const int l15 = lane & 15, l4 = lane >> 4;
  const int wr = wid >> 1, wc = wid & 1;

  const int nwg = gridDim.x * gridDim.y;
  int lid = blockIdx.y * gridDim.x + blockIdx.x;
  lid = (lid & 7) * (nwg >> 3) + (lid >> 3);
  const int m0 = (lid / gridDim.x) * 128, n0 = (lid % gridDim.x) * 128;

  const int ra0 = t >> 2,         ca0 = (t & 3) ^ ((ra0 >> 1) & 3);
  const int ra1 = (t + 256) >> 2, ca1 = (t & 3) ^ ((ra1 >> 1) & 3);
  const u16* Ag0 = A + (size_t)(m0 + ra0) * K + ca0 * 8;
  const u16* Ag1 = A + (size_t)(m0 + ra1) * K + ca1 * 8;
  const u16* Bg0 = B + (size_t)(n0 + ra0) * K + ca0 * 8;
  const u16* Bg1 = B + (size_t)(n0 + ra1) * K + ca1 * 8;

#define STAGE(k0_, buf_) do {                                                 \
    GLD16(Ag0 + (k0_), &As[buf_][t * 8]);                                     \
    GLD16(Ag1 + (k0_), &As[buf_][2048 + t * 8]);                              \
    GLD16(Bg0 + (k0_), &Bs[buf_][t * 8]);                                     \
    GLD16(Bg1 + (k0_), &Bs[buf_][2048 + t * 8]);                              \
  } while (0)

  const int nk = K >> 5;
  const int ks = (l15 >> 1) & 3;
  const int coff = ((l4 ^ ks) << 3);

  f32x4 acc[4][4] = {};

  STAGE(0, 0);
  STAGE(32, 1);

  for (int j = 0; j < nk; ++j) {
    const int cur = j & 1;
    if (j + 1 < nk) asm volatile("s_waitcnt vmcnt(4)" ::: "memory");
    else            asm volatile("s_waitcnt vmcnt(0)" ::: "memory");
    __builtin_amdgcn_s_barrier();
    __builtin_amdgcn_sched_barrier(0);

    bf16x8 af[4], bfr[4];
#pragma unroll
    for (int mi = 0; mi < 4; ++mi)
      af[mi] = *(const bf16x8*)&As[cur][(wr * 64 + mi * 16 + l15) * 32 + coff];
#pragma unroll
    for (int ni = 0; ni < 4; ++ni)
      bfr[ni] = *(const bf16x8*)&Bs[cur][(wc * 64 + ni * 16 + l15) * 32 + coff];
    __builtin_amdgcn_s_setprio(1);
#pragma unroll
    for (int mi = 0; mi < 4; ++mi)
#pragma unroll
      for (int ni = 0; ni < 4; ++ni)
        acc[mi][ni] = MFMA16(af[mi], bfr[ni], acc[mi][ni]);
    __builtin_amdgcn_s_setprio(0);

    __builtin_amdgcn_s_barrier();
    if (j + 2 < nk) STAGE((j + 2) << 5, cur);
  }

  const int crow = m0 + wr * 64 + (l4 << 2);
  const int ccol = n0 + wc * 64 + l15;
#pragma unroll
  for (int mi = 0; mi < 4; ++mi)
#pragma unroll
    for (int ni = 0; ni < 4; ++ni)
#pragma unroll
      for (int r = 0; r < 4; ++r)
        cstore(C, (size_t)(crow + mi * 16 + r) * N + (ccol + ni * 16), acc[mi][ni][r]);
#undef STAGE
}

// ---------------------------------------------------------------- RMSNorm + RoPE
// q heads pre-scaled by (1/sqrt(128))*log2(e) -> QK^T lands in exp2 domain.
__global__ __launch_bounds__(256) void rmsrope_kernel(u16* __restrict__ qkv) {
  const int t = threadIdx.x;
  const int lane = t & 63;
  const int gw = blockIdx.x * 4 + (t >> 6);
  const int row = gw / 20;
  const int hd = gw - row * 20;
  const int col = (hd < 16) ? hd * 128 : 2048 + (hd - 16) * 128;
  const size_t base = (size_t)row * 3072 + col;
  float x1 = b2f(qkv[base + lane]);
  float x2 = b2f(qkv[base + 64 + lane]);
  float ss = x1 * x1 + x2 * x2;
#pragma unroll
  for (int off = 32; off >= 1; off >>= 1) ss += __shfl_xor(ss, off, 64);
  const float qsc = (hd < 16) ? (0.08838834764831845f * 1.44269504088896340f)
                              : 1.0f;
  const float sc = rsqrtf(ss * (1.0f / 128.0f) + 1e-6f) * qsc;
  const int pos = row & 2047;
  const float inv_freq = exp2f(-(float)lane * (13.287712379549449f / 64.0f));
  float sn, cs;
  sincosf((float)pos * inv_freq, &sn, &cs);
  const float a = x1 * sc, b2 = x2 * sc;
  __hip_bfloat16 o1 = __float2bfloat16(a * cs - b2 * sn);
  __hip_bfloat16 o2 = __float2bfloat16(a * sn + b2 * cs);
  qkv[base + lane] = *(u16*)&o1;
  qkv[base + 64 + lane] = *(u16*)&o2;
}

// ---------------------------------------------------------------- V transpose
// vt[g=b*4+kvh][d=128][s=2048], sigma-permuted s within each 64-group.
__global__ __launch_bounds__(256) void vtrans_kernel(const u16* __restrict__ qkv,
                                                     u16* __restrict__ vt) {
  __shared__ u16 Ls[64 * 130];
  const int t = threadIdx.x;
  const int g = blockIdx.x & 7, sb = blockIdx.x >> 3;
  const int b = g >> 2, kvh = g & 3;
  const int vcol = 2560 + kvh * 128;
  {
    const int row = t >> 4, dch = t & 15;
    const u16* src = qkv + (size_t)(b * 2048 + sb * 64 + row) * 3072 + vcol + dch * 8;
#pragma unroll
    for (int it = 0; it < 4; ++it) {
      bf16x8 v = *(const bf16x8*)(src + (size_t)it * 16 * 3072);
      *(bf16x8*)&Ls[(row + it * 16) * 130 + dch * 8] = v;
    }
  }
  __syncthreads();
  const int c = t & 7, d0 = t >> 3;
  const int k0 = 4 * (8 * (c >> 2) + 4 * ((c >> 1) & 1) + (c & 1));
#pragma unroll
  for (int it = 0; it < 4; ++it) {
    const int d = d0 + 32 * it;
    u16 v[8];
#pragma unroll
    for (int e = 0; e < 8; ++e)
      v[e] = Ls[(k0 + (e & 3) + 8 * (e >> 2)) * 130 + d];
    u64 lo = (u64)v[0] | ((u64)v[1] << 16) | ((u64)v[2] << 32) | ((u64)v[3] << 48);
    u64 hi = (u64)v[4] | ((u64)v[5] << 16) | ((u64)v[6] << 32) | ((u64)v[7] << 48);
    u64* dst = (u64*)(vt + ((size_t)g * 128 + d) * 2048 + sb * 64 + c * 8);
    dst[0] = lo; dst[1] = hi;
  }
}

// ---------------------------------------------------------------- flash attention
// (measured best, r10/r13): 512 blocks x 256 thr = 4 waves (2 qg x 2
// k-halves); q64-tile pair (j, 31-j) sequential (33 iters); counted vmcnt(8)
// pipeline, 2 barriers/iter; zero-shuffle PV via sigma-ordered vt; XOR bank
// swizzles; defer-max; exp2-domain Q prescale.
__global__ __launch_bounds__(256, 2) void attn_kernel(const u16* __restrict__ qkv,
                                                      const u16* __restrict__ vt,
                                                      u16* __restrict__ ao) {
  __shared__ u16 Ks[2][64 * 128];   // [k][d], 16B chunks XORed by k&7 (32K)
  __shared__ u16 Vt[2][128 * 64];   // [d][sigma(k)], chunks XORed by d&7 (32K)

  const int t = threadIdx.x;
  const int lane = t & 63, w = t >> 6;
  const int l31 = lane & 31, hi = lane >> 5;
  const int qg = w >> 1, hi2 = w & 1;

  const int bid = blockIdx.x;
  const int g = bid & 7;                  // XCD group = (b, kvh)
  const int b = g >> 2, kvh = g & 3;
  const int idx = bid >> 3;
  const int h = kvh * 4 + (idx & 3);
  const int j = idx >> 2;                 // 0..15 -> pair (j, 31-j)

  const int kcol = 2048 + kvh * 128;
  const u16* vtg = vt + (size_t)g * 128 * 2048;

  const int krow_s = t >> 4, kchk = t & 15;   // K staging (4 GLD/thread)
  const int vd = t >> 3, vc = t & 7;          // V staging (4 GLD/thread)

#define STAGE_K(kb_, buf_) do {                                               \
    const size_t rb_ = (size_t)(b * 2048 + (kb_) * 64);                       \
    _Pragma("unroll")                                                         \
    for (int j_ = 0; j_ < 4; ++j_) {                                          \
      const int row_ = j_ * 16 + krow_s;                                      \
      GLD16(qkv + (rb_ + row_) * 3072 + kcol + ((kchk ^ (row_ & 7)) << 3),    \
            &Ks[buf_][(j_ * 256 + t) << 3]);                                  \
    } } while (0)

#define STAGE_V(kb_, buf_) do {                                               \
    _Pragma("unroll")                                                         \
    for (int j_ = 0; j_ < 4; ++j_) {                                          \
      const int d_ = j_ * 32 + vd;                                            \
      GLD16(vtg + (size_t)d_ * 2048 + (kb_) * 64 + ((vc ^ (d_ & 7)) << 3),    \
            &Vt[buf_][(j_ * 256 + t) << 3]);                                  \
    } } while (0)

  for (int ph = 0; ph < 2; ++ph) {
    const int qt64 = ph ? (31 - j) : j;
    const int q0 = qt64 * 64;
    const int nt = qt64 + 1;
    const int qrow = q0 + 32 * qg + l31;

    // Q fragments (B operand): col=q, k = st*16 + hi*8 + e (pre-scaled)
    bf16x8 qf[8];
    {
      const u16* qp = qkv + (size_t)(b * 2048 + qrow) * 3072 + h * 128 + hi * 8;
#pragma unroll
      for (int st = 0; st < 8; ++st) qf[st] = *(const bf16x8*)(qp + st * 16);
    }

    f32x16 o[4];
#pragma unroll
    for (int dt = 0; dt < 4; ++dt)
#pragma unroll
      for (int i = 0; i < 16; ++i) o[dt][i] = 0.f;
    float m2 = -1e30f, l = 0.f;

    // prologue: stage batches 0 and 1
    STAGE_K(0, 0);
    STAGE_V(0, 0);
    if (nt > 1) { STAGE_K(1, 1); STAGE_V(1, 1); }

    for (int kb = 0; kb < nt; ++kb) {
      const int cur = kb & 1;
      if (kb + 1 < nt) asm volatile("s_waitcnt vmcnt(8)" ::: "memory");
      else             asm volatile("s_waitcnt vmcnt(0)" ::: "memory");
      __builtin_amdgcn_s_barrier();
      __builtin_amdgcn_sched_barrier(0);

      // ---- S^T = K_half Q^T  (rows k of this wave's 32-half, cols q)
      f32x16 s;
#pragma unroll
      for (int i = 0; i < 16; ++i) s[i] = 0.f;
      const int kbase = (32 * hi2 + l31) * 128;
      const int ksw = l31 & 7;
      __builtin_amdgcn_s_setprio(1);
#pragma unroll
      for (int st = 0; st < 8; ++st) {
        bf16x8 ka = *(const bf16x8*)&Ks[cur][kbase + (((2 * st + hi) ^ ksw) << 3)];
        s = MFMA32(ka, qf[st], s);
      }
      __builtin_amdgcn_s_setprio(0);

      // ---- mask (diag only), max3-tree row max
      const bool nomask = (kb < qt64) || (hi2 == 0 && qg == 1);
      if (!nomask) {
#pragma unroll
        for (int i = 0; i < 16; ++i) {
          const int kr = kb * 64 + 32 * hi2 + (i & 3) + 8 * (i >> 2) + 4 * hi;
          s[i] = (kr <= qrow) ? s[i] : -INFINITY;
        }
      }
      float a0 = fmax3(s[0], s[1], s[2]);
      float a1 = fmax3(s[3], s[4], s[5]);
      float a2 = fmax3(s[6], s[7], s[8]);
      float a3 = fmax3(s[9], s[10], s[11]);
      float a4 = fmax3(s[12], s[13], s[14]);
      float b0 = fmax3(a0, a1, s[15]);
      float b1 = fmax3(a2, a3, a4);
      float pm = fmaxf(b0, b1);
      pm = fmaxf(pm, __shfl_xor(pm, 32));
      // ---- defer-max rescale
      if (!__all(pm <= m2 + 8.f)) {
        const float m2n = fmaxf(m2, pm);
        const float fc = exp2f(m2 - m2n);
        m2 = m2n; l *= fc;
#pragma unroll
        for (int dt = 0; dt < 4; ++dt)
#pragma unroll
          for (int i = 0; i < 16; ++i) o[dt][i] *= fc;
      }
      // ---- P = exp2(z - m2), tree local sum (cross-hi deferred)
#pragma unroll
      for (int i = 0; i < 16; ++i) s[i] = exp2f(s[i] - m2);
      float t8[8];
#pragma unroll
      for (int i = 0; i < 8; ++i) t8[i] = s[i] + s[i + 8];
#pragma unroll
      for (int i = 0; i < 4; ++i) t8[i] = t8[i] + t8[i + 4];
      l += (t8[0] + t8[1]) + (t8[2] + t8[3]);
      // ---- P C-regs -> B-operand directly (sigma order, perm pack)
      union PB { u32 wd[4]; bf16x8 v; } p0u, p1u;
#pragma unroll
      for (int q_ = 0; q_ < 4; ++q_) {
        p0u.wd[q_] = pk2(s[2 * q_],     s[2 * q_ + 1]);
        p1u.wd[q_] = pk2(s[8 + 2 * q_], s[8 + 2 * q_ + 1]);
      }
      // ---- O^T += V^T_half P_half  (rows d, cols q)
      __builtin_amdgcn_s_setprio(1);
#pragma unroll
      for (int dt = 0; dt < 4; ++dt) {
        const int vrow = (dt * 32 + l31) * 64;
        const int dsw = l31 & 7;
        bf16x8 va0 = *(const bf16x8*)&Vt[cur][vrow + (((4 * hi2 + hi) ^ dsw) << 3)];
        o[dt] = MFMA32(va0, p0u.v, o[dt]);
        bf16x8 va1 = *(const bf16x8*)&Vt[cur][vrow + (((4 * hi2 + 2 + hi) ^ dsw) << 3)];
        o[dt] = MFMA32(va1, p1u.v, o[dt]);
      }
      __builtin_amdgcn_s_setprio(0);

      __builtin_amdgcn_s_barrier();          // all waves done reading buf[cur]
      if (kb + 2 < nt) { STAGE_K(kb + 2, cur); STAGE_V(kb + 2, cur); }
    }

    // ---- in-block merge of the two k-halves (per q-group)
    __syncthreads();                 // all compute done; Ks/Vt reusable
    const float l_tot = l + __shfl_xor(l, 32);
    float* Mrg = (float*)&Ks[0][0];
    float* Mlb = (float*)&Vt[0][0];
    const int sw8 = l31 & 7;
    if (hi2) {
#pragma unroll
      for (int dt = 0; dt < 4; ++dt) {
        const int rbase = ((qg * 4 + dt) * 32 + l31) * 32;
#pragma unroll
        for (int m_ = 0; m_ < 4; ++m_) {
          f32x4 cv;
          cv[0] = o[dt][4 * m_ + 0]; cv[1] = o[dt][4 * m_ + 1];
          cv[2] = o[dt][4 * m_ + 2]; cv[3] = o[dt][4 * m_ + 3];
          *(f32x4*)&Mrg[rbase + (((hi * 4 + m_) ^ sw8) << 2)] = cv;
        }
      }
      if (hi == 0) {
        Mlb[qg * 64 + l31] = m2;
        Mlb[qg * 64 + 32 + l31] = l_tot;
      }
    }
    __syncthreads();
    if (!hi2) {
      const float m1 = Mlb[qg * 64 + l31];
      const float l1 = Mlb[qg * 64 + 32 + l31];
      const float ms = fmaxf(m2, m1);
      const float w0 = exp2f(m2 - ms), w1 = exp2f(m1 - ms);
      const float inv = 1.f / (w0 * l_tot + w1 * l1);
      const float aw0 = w0 * inv, aw1 = w1 * inv;
      const size_t orow = (size_t)(b * 2048 + qrow) * 2048 + h * 128;
#pragma unroll
      for (int dt = 0; dt < 4; ++dt) {
        const int rbase = ((qg * 4 + dt) * 32 + l31) * 32;
#pragma unroll
        for (int m_ = 0; m_ < 4; ++m_) {
          f32x4 o1v = *(const f32x4*)&Mrg[rbase + (((hi * 4 + m_) ^ sw8) << 2)];
          u64 val = 0;
#pragma unroll
          for (int r = 0; r < 4; ++r) {
            __hip_bfloat16 hb =
                __float2bfloat16(aw0 * o[dt][4 * m_ + r] + aw1 * o1v[r]);
            val |= (u64)(*(u16*)&hb) << (16 * r);
          }
          *(u64*)&ao[orow + dt * 32 + 8 * m_ + 4 * hi] = val;
        }
      }
    }
    __syncthreads();                 // protect Mrg/Mlb before next-phase staging
  }
#undef STAGE_K
#undef STAGE_V
}

// ---------------------------------------------------------------- launch
extern "C" void kernel_launch(void* const* d_in, const int* in_sizes, int n_in,
                              void* d_out, int out_size, void* d_ws, size_t ws_size,
                              hipStream_t stream) {
  const float* x  = (const float*)d_in[0];
  const float* wq = (const float*)d_in[2];
  const float* wk = (const float*)d_in[3];
  const float* wv = (const float*)d_in[4];
  const float* wo = (const float*)d_in[5];
  float* out = (float*)d_out;

  u16* xb   = (u16*)d_ws;                       // x bf16   [4096][2048]
  u16* wqkv = xb + (size_t)8388608;             // W bf16   [3072][2048]
  u16* qkv  = wqkv + (size_t)6291456;           // qkv      [4096][3072]
  u16* vtg  = qkv + (size_t)12582912;           // V^T      [8][128][2048]
  u16* wob  = vtg + (size_t)2097152;            // wo bf16  [2048][2048]
  u16* ao   = xb;                               // attn out [4096][2048] (reuse xb)

  cast_all<<<18432, 256, 0, stream>>>(x, wq, wk, wv, wo, xb, wqkv, wob);

  gemm_2ph<u16><<<dim3(12, 16), 512, 0, stream>>>(xb, wqkv, qkv, 4096, 3072, 2048);

  rmsrope_kernel<<<20480, 256, 0, stream>>>(qkv);
  vtrans_kernel<<<256, 256, 0, stream>>>(qkv, vtg);

  attn_kernel<<<512, 256, 0, stream>>>(qkv, vtg, ao);

  gemm_sm<float><<<dim3(16, 32), 256, 0, stream>>>(ao, wob, out, 4096, 2048, 2048);
}

// Round 16
// 201.977 us; speedup vs baseline: 1.0086x; 1.0086x over previous
//
#include <hip/hip_runtime.h>
#include <hip/hip_bf16.h>

typedef unsigned short u16;
typedef unsigned int   u32;
typedef unsigned long long u64;
typedef __attribute__((ext_vector_type(8))) short bf16x8;
typedef __attribute__((ext_vector_type(4))) float f32x4;
typedef __attribute__((ext_vector_type(16))) float f32x16;

#define MFMA16(a,b,c) __builtin_amdgcn_mfma_f32_16x16x32_bf16((a),(b),(c),0,0,0)
#define MFMA32(a,b,c) __builtin_amdgcn_mfma_f32_32x32x16_bf16((a),(b),(c),0,0,0)

#define GLD16(gp, lp) __builtin_amdgcn_global_load_lds( \
    (const __attribute__((address_space(1))) void*)(gp), \
    (__attribute__((address_space(3))) void*)(lp), 16, 0, 0)

__device__ inline u32 pkbf(float a, float b) {
  __hip_bfloat16 ha = __float2bfloat16(a), hb = __float2bfloat16(b);
  return (u32)(*(u16*)&ha) | ((u32)(*(u16*)&hb) << 16);
}
__device__ inline float b2f(u16 x) {
  __hip_bfloat16 h; *(u16*)&h = x; return __bfloat162float(h);
}
// fast bf16 pair pack: round (+0x8000) then byte-perm the two high halves
__device__ inline u32 pk2(float a, float b) {
  u32 ua = __builtin_bit_cast(u32, a) + 0x8000u;
  u32 ub = __builtin_bit_cast(u32, b) + 0x8000u;
  return __builtin_amdgcn_perm(ub, ua, 0x07060302u);
}
__device__ inline float fmax3(float a, float b, float c) {
  return fmaxf(fmaxf(a, b), c);
}

// ---------------------------------------------------------------- fused casts
__global__ __launch_bounds__(256) void cast_all(const float* __restrict__ x,
                                                const float* __restrict__ wq,
                                                const float* __restrict__ wk,
                                                const float* __restrict__ wv,
                                                const float* __restrict__ wo,
                                                u16* __restrict__ xb,
                                                u16* __restrict__ wqkv,
                                                u16* __restrict__ wob) {
  int i = blockIdx.x * 256 + threadIdx.x;
  const float* src; u16* dst; int off;
  if (i < 2097152)      { src = x;  dst = xb;                 off = 0; }
  else if (i < 3145728) { src = wq; dst = wqkv;               off = 2097152; }
  else if (i < 3407872) { src = wk; dst = wqkv + 4194304;     off = 3145728; }
  else if (i < 3670016) { src = wv; dst = wqkv + 5242880;     off = 3407872; }
  else                  { src = wo; dst = wob;                off = 3670016; }
  const int k = i - off;
  float4 v = reinterpret_cast<const float4*>(src)[k];
  uint2 pk; pk.x = pkbf(v.x, v.y); pk.y = pkbf(v.z, v.w);
  reinterpret_cast<uint2*>(dst)[k] = pk;
}

__device__ inline void cstore(u16* C, size_t i, float v) {
  __hip_bfloat16 h = __float2bfloat16(v); C[i] = *(u16*)&h;
}
__device__ inline void cstore(float* C, size_t i, float v) { C[i] = v; }

// ---------------------------------------------------------------- GEMM 128x128
// C = A * B^T. 256 thr = 4 waves (2M x 2N). Counted vmcnt(4) + raw s_barrier
// pipeline; 0-conflict chunk swizzle. High blocks/CU (3-4) is the measured
// win (r11: 1/CU = -40%; r13: gemm_sm beat gemm_big on gemm2).
template<typename OutT>
__global__ __launch_bounds__(256, 4) void gemm_sm(const u16* __restrict__ A,
                                                  const u16* __restrict__ B,
                                                  OutT* __restrict__ C,
                                                  int M, int N, int K) {
  __shared__ u16 As[2][128 * 32];   // 16K
  __shared__ u16 Bs[2][128 * 32];   // 16K

  const int t = threadIdx.x;
  const int lane = t & 63, wid = t >> 6;
  const int l15 = lane & 15, l4 = lane >> 4;
  const int wr = wid >> 1, wc = wid & 1;

  const int nwg = gridDim.x * gridDim.y;
  int lid = blockIdx.y * gridDim.x + blockIdx.x;
  lid = (lid & 7) * (nwg >> 3) + (lid >> 3);
  const int m0 = (lid / gridDim.x) * 128, n0 = (lid % gridDim.x) * 128;

  const int ra0 = t >> 2,         ca0 = (t & 3) ^ ((ra0 >> 1) & 3);
  const int ra1 = (t + 256) >> 2, ca1 = (t & 3) ^ ((ra1 >> 1) & 3);
  const u16* Ag0 = A + (size_t)(m0 + ra0) * K + ca0 * 8;
  const u16* Ag1 = A + (size_t)(m0 + ra1) * K + ca1 * 8;
  const u16* Bg0 = B + (size_t)(n0 + ra0) * K + ca0 * 8;
  const u16* Bg1 = B + (size_t)(n0 + ra1) * K + ca1 * 8;

#define STAGE(k0_, buf_) do {                                                 \
    GLD16(Ag0 + (k0_), &As[buf_][t * 8]);                                     \
    GLD16(Ag1 + (k0_), &As[buf_][2048 + t * 8]);                              \
    GLD16(Bg0 + (k0_), &Bs[buf_][t * 8]);                                     \
    GLD16(Bg1 + (k0_), &Bs[buf_][2048 + t * 8]);                              \
  } while (0)

  const int nk = K >> 5;
  const int ks = (l15 >> 1) & 3;
  const int coff = ((l4 ^ ks) << 3);

  f32x4 acc[4][4] = {};

  STAGE(0, 0);
  STAGE(32, 1);

  for (int j = 0; j < nk; ++j) {
    const int cur = j & 1;
    if (j + 1 < nk) asm volatile("s_waitcnt vmcnt(4)" ::: "memory");
    else            asm volatile("s_waitcnt vmcnt(0)" ::: "memory");
    __builtin_amdgcn_s_barrier();
    __builtin_amdgcn_sched_barrier(0);

    bf16x8 af[4], bfr[4];
#pragma unroll
    for (int mi = 0; mi < 4; ++mi)
      af[mi] = *(const bf16x8*)&As[cur][(wr * 64 + mi * 16 + l15) * 32 + coff];
#pragma unroll
    for (int ni = 0; ni < 4; ++ni)
      bfr[ni] = *(const bf16x8*)&Bs[cur][(wc * 64 + ni * 16 + l15) * 32 + coff];
    __builtin_amdgcn_s_setprio(1);
#pragma unroll
    for (int mi = 0; mi < 4; ++mi)
#pragma unroll
      for (int ni = 0; ni < 4; ++ni)
        acc[mi][ni] = MFMA16(af[mi], bfr[ni], acc[mi][ni]);
    __builtin_amdgcn_s_setprio(0);

    __builtin_amdgcn_s_barrier();
    if (j + 2 < nk) STAGE((j + 2) << 5, cur);
  }

  const int crow = m0 + wr * 64 + (l4 << 2);
  const int ccol = n0 + wc * 64 + l15;
#pragma unroll
  for (int mi = 0; mi < 4; ++mi)
#pragma unroll
    for (int ni = 0; ni < 4; ++ni)
#pragma unroll
      for (int r = 0; r < 4; ++r)
        cstore(C, (size_t)(crow + mi * 16 + r) * N + (ccol + ni * 16), acc[mi][ni][r]);
#undef STAGE
}

// ---------------------------------------------------------------- RMSNorm+RoPE | Vtrans
// Merged launch: blocks [0,20480) do rmsrope (qkv cols < 2560); blocks
// [20480, 20736) do the V transpose (reads cols >= 2560) -> independent,
// overlap freely. q heads pre-scaled by (1/sqrt(128))*log2(e).
__global__ __launch_bounds__(256) void rope_vtrans(u16* __restrict__ qkv,
                                                   u16* __restrict__ vt) {
  __shared__ u16 Ls[64 * 130];
  const int bid = blockIdx.x;
  const int t = threadIdx.x;
  if (bid < 20480) {
    const int lane = t & 63;
    const int gw = bid * 4 + (t >> 6);
    const int row = gw / 20;
    const int hd = gw - row * 20;
    const int col = (hd < 16) ? hd * 128 : 2048 + (hd - 16) * 128;
    const size_t base = (size_t)row * 3072 + col;
    float x1 = b2f(qkv[base + lane]);
    float x2 = b2f(qkv[base + 64 + lane]);
    float ss = x1 * x1 + x2 * x2;
#pragma unroll
    for (int off = 32; off >= 1; off >>= 1) ss += __shfl_xor(ss, off, 64);
    const float qsc = (hd < 16) ? (0.08838834764831845f * 1.44269504088896340f)
                                : 1.0f;
    const float sc = rsqrtf(ss * (1.0f / 128.0f) + 1e-6f) * qsc;
    const int pos = row & 2047;
    const float inv_freq = exp2f(-(float)lane * (13.287712379549449f / 64.0f));
    float sn, cs;
    sincosf((float)pos * inv_freq, &sn, &cs);
    const float a = x1 * sc, b2 = x2 * sc;
    __hip_bfloat16 o1 = __float2bfloat16(a * cs - b2 * sn);
    __hip_bfloat16 o2 = __float2bfloat16(a * sn + b2 * cs);
    qkv[base + lane] = *(u16*)&o1;
    qkv[base + 64 + lane] = *(u16*)&o2;
  } else {
    const int vb = bid - 20480;
    const int g = vb & 7, sb = vb >> 3;
    const int b = g >> 2, kvh = g & 3;
    const int vcol = 2560 + kvh * 128;
    {
      const int row = t >> 4, dch = t & 15;
      const u16* src = qkv + (size_t)(b * 2048 + sb * 64 + row) * 3072 + vcol + dch * 8;
#pragma unroll
      for (int it = 0; it < 4; ++it) {
        bf16x8 v = *(const bf16x8*)(src + (size_t)it * 16 * 3072);
        *(bf16x8*)&Ls[(row + it * 16) * 130 + dch * 8] = v;
      }
    }
    __syncthreads();
    const int c = t & 7, d0 = t >> 3;
    const int k0 = 4 * (8 * (c >> 2) + 4 * ((c >> 1) & 1) + (c & 1));
#pragma unroll
    for (int it = 0; it < 4; ++it) {
      const int d = d0 + 32 * it;
      u16 v[8];
#pragma unroll
      for (int e = 0; e < 8; ++e)
        v[e] = Ls[(k0 + (e & 3) + 8 * (e >> 2)) * 130 + d];
      u64 lo = (u64)v[0] | ((u64)v[1] << 16) | ((u64)v[2] << 32) | ((u64)v[3] << 48);
      u64 hi = (u64)v[4] | ((u64)v[5] << 16) | ((u64)v[6] << 32) | ((u64)v[7] << 48);
      u64* dst = (u64*)(vt + ((size_t)g * 128 + d) * 2048 + sb * 64 + c * 8);
      dst[0] = lo; dst[1] = hi;
    }
  }
}

// ---------------------------------------------------------------- flash attention
// (measured best, r10/r13): 512 blocks x 256 thr = 4 waves (2 qg x 2
// k-halves); q64-tile pair (j, 31-j) sequential (33 iters); counted vmcnt(8)
// pipeline, 2 barriers/iter; zero-shuffle PV via sigma-ordered vt; XOR bank
// swizzles; defer-max; exp2-domain Q prescale.
__global__ __launch_bounds__(256, 2) void attn_kernel(const u16* __restrict__ qkv,
                                                      const u16* __restrict__ vt,
                                                      u16* __restrict__ ao) {
  __shared__ u16 Ks[2][64 * 128];   // [k][d], 16B chunks XORed by k&7 (32K)
  __shared__ u16 Vt[2][128 * 64];   // [d][sigma(k)], chunks XORed by d&7 (32K)

  const int t = threadIdx.x;
  const int lane = t & 63, w = t >> 6;
  const int l31 = lane & 31, hi = lane >> 5;
  const int qg = w >> 1, hi2 = w & 1;

  const int bid = blockIdx.x;
  const int g = bid & 7;                  // XCD group = (b, kvh)
  const int b = g >> 2, kvh = g & 3;
  const int idx = bid >> 3;
  const int h = kvh * 4 + (idx & 3);
  const int j = idx >> 2;                 // 0..15 -> pair (j, 31-j)

  const int kcol = 2048 + kvh * 128;
  const u16* vtg = vt + (size_t)g * 128 * 2048;

  const int krow_s = t >> 4, kchk = t & 15;   // K staging (4 GLD/thread)
  const int vd = t >> 3, vc = t & 7;          // V staging (4 GLD/thread)

#define STAGE_K(kb_, buf_) do {                                               \
    const size_t rb_ = (size_t)(b * 2048 + (kb_) * 64);                       \
    _Pragma("unroll")                                                         \
    for (int j_ = 0; j_ < 4; ++j_) {                                          \
      const int row_ = j_ * 16 + krow_s;                                      \
      GLD16(qkv + (rb_ + row_) * 3072 + kcol + ((kchk ^ (row_ & 7)) << 3),    \
            &Ks[buf_][(j_ * 256 + t) << 3]);                                  \
    } } while (0)

#define STAGE_V(kb_, buf_) do {                                               \
    _Pragma("unroll")                                                         \
    for (int j_ = 0; j_ < 4; ++j_) {                                          \
      const int d_ = j_ * 32 + vd;                                            \
      GLD16(vtg + (size_t)d_ * 2048 + (kb_) * 64 + ((vc ^ (d_ & 7)) << 3),    \
            &Vt[buf_][(j_ * 256 + t) << 3]);                                  \
    } } while (0)

  for (int ph = 0; ph < 2; ++ph) {
    const int qt64 = ph ? (31 - j) : j;
    const int q0 = qt64 * 64;
    const int nt = qt64 + 1;
    const int qrow = q0 + 32 * qg + l31;

    // Q fragments (B operand): col=q, k = st*16 + hi*8 + e (pre-scaled)
    bf16x8 qf[8];
    {
      const u16* qp = qkv + (size_t)(b * 2048 + qrow) * 3072 + h * 128 + hi * 8;
#pragma unroll
      for (int st = 0; st < 8; ++st) qf[st] = *(const bf16x8*)(qp + st * 16);
    }

    f32x16 o[4];
#pragma unroll
    for (int dt = 0; dt < 4; ++dt)
#pragma unroll
      for (int i = 0; i < 16; ++i) o[dt][i] = 0.f;
    float m2 = -1e30f, l = 0.f;

    // prologue: stage batches 0 and 1
    STAGE_K(0, 0);
    STAGE_V(0, 0);
    if (nt > 1) { STAGE_K(1, 1); STAGE_V(1, 1); }

    for (int kb = 0; kb < nt; ++kb) {
      const int cur = kb & 1;
      if (kb + 1 < nt) asm volatile("s_waitcnt vmcnt(8)" ::: "memory");
      else             asm volatile("s_waitcnt vmcnt(0)" ::: "memory");
      __builtin_amdgcn_s_barrier();
      __builtin_amdgcn_sched_barrier(0);

      // ---- S^T = K_half Q^T  (rows k of this wave's 32-half, cols q)
      f32x16 s;
#pragma unroll
      for (int i = 0; i < 16; ++i) s[i] = 0.f;
      const int kbase = (32 * hi2 + l31) * 128;
      const int ksw = l31 & 7;
      __builtin_amdgcn_s_setprio(1);
#pragma unroll
      for (int st = 0; st < 8; ++st) {
        bf16x8 ka = *(const bf16x8*)&Ks[cur][kbase + (((2 * st + hi) ^ ksw) << 3)];
        s = MFMA32(ka, qf[st], s);
      }
      __builtin_amdgcn_s_setprio(0);

      // ---- mask (diag only), max3-tree row max
      const bool nomask = (kb < qt64) || (hi2 == 0 && qg == 1);
      if (!nomask) {
#pragma unroll
        for (int i = 0; i < 16; ++i) {
          const int kr = kb * 64 + 32 * hi2 + (i & 3) + 8 * (i >> 2) + 4 * hi;
          s[i] = (kr <= qrow) ? s[i] : -INFINITY;
        }
      }
      float a0 = fmax3(s[0], s[1], s[2]);
      float a1 = fmax3(s[3], s[4], s[5]);
      float a2 = fmax3(s[6], s[7], s[8]);
      float a3 = fmax3(s[9], s[10], s[11]);
      float a4 = fmax3(s[12], s[13], s[14]);
      float b0 = fmax3(a0, a1, s[15]);
      float b1 = fmax3(a2, a3, a4);
      float pm = fmaxf(b0, b1);
      pm = fmaxf(pm, __shfl_xor(pm, 32));
      // ---- defer-max rescale
      if (!__all(pm <= m2 + 8.f)) {
        const float m2n = fmaxf(m2, pm);
        const float fc = exp2f(m2 - m2n);
        m2 = m2n; l *= fc;
#pragma unroll
        for (int dt = 0; dt < 4; ++dt)
#pragma unroll
          for (int i = 0; i < 16; ++i) o[dt][i] *= fc;
      }
      // ---- P = exp2(z - m2), tree local sum (cross-hi deferred)
#pragma unroll
      for (int i = 0; i < 16; ++i) s[i] = exp2f(s[i] - m2);
      float t8[8];
#pragma unroll
      for (int i = 0; i < 8; ++i) t8[i] = s[i] + s[i + 8];
#pragma unroll
      for (int i = 0; i < 4; ++i) t8[i] = t8[i] + t8[i + 4];
      l += (t8[0] + t8[1]) + (t8[2] + t8[3]);
      // ---- P C-regs -> B-operand directly (sigma order, perm pack)
      union PB { u32 wd[4]; bf16x8 v; } p0u, p1u;
#pragma unroll
      for (int q_ = 0; q_ < 4; ++q_) {
        p0u.wd[q_] = pk2(s[2 * q_],     s[2 * q_ + 1]);
        p1u.wd[q_] = pk2(s[8 + 2 * q_], s[8 + 2 * q_ + 1]);
      }
      // ---- O^T += V^T_half P_half  (rows d, cols q)
      __builtin_amdgcn_s_setprio(1);
#pragma unroll
      for (int dt = 0; dt < 4; ++dt) {
        const int vrow = (dt * 32 + l31) * 64;
        const int dsw = l31 & 7;
        bf16x8 va0 = *(const bf16x8*)&Vt[cur][vrow + (((4 * hi2 + hi) ^ dsw) << 3)];
        o[dt] = MFMA32(va0, p0u.v, o[dt]);
        bf16x8 va1 = *(const bf16x8*)&Vt[cur][vrow + (((4 * hi2 + 2 + hi) ^ dsw) << 3)];
        o[dt] = MFMA32(va1, p1u.v, o[dt]);
      }
      __builtin_amdgcn_s_setprio(0);

      __builtin_amdgcn_s_barrier();          // all waves done reading buf[cur]
      if (kb + 2 < nt) { STAGE_K(kb + 2, cur); STAGE_V(kb + 2, cur); }
    }

    // ---- in-block merge of the two k-halves (per q-group)
    __syncthreads();                 // all compute done; Ks/Vt reusable
    const float l_tot = l + __shfl_xor(l, 32);
    float* Mrg = (float*)&Ks[0][0];
    float* Mlb = (float*)&Vt[0][0];
    const int sw8 = l31 & 7;
    if (hi2) {
#pragma unroll
      for (int dt = 0; dt < 4; ++dt) {
        const int rbase = ((qg * 4 + dt) * 32 + l31) * 32;
#pragma unroll
        for (int m_ = 0; m_ < 4; ++m_) {
          f32x4 cv;
          cv[0] = o[dt][4 * m_ + 0]; cv[1] = o[dt][4 * m_ + 1];
          cv[2] = o[dt][4 * m_ + 2]; cv[3] = o[dt][4 * m_ + 3];
          *(f32x4*)&Mrg[rbase + (((hi * 4 + m_) ^ sw8) << 2)] = cv;
        }
      }
      if (hi == 0) {
        Mlb[qg * 64 + l31] = m2;
        Mlb[qg * 64 + 32 + l31] = l_tot;
      }
    }
    __syncthreads();
    if (!hi2) {
      const float m1 = Mlb[qg * 64 + l31];
      const float l1 = Mlb[qg * 64 + 32 + l31];
      const float ms = fmaxf(m2, m1);
      const float w0 = exp2f(m2 - ms), w1 = exp2f(m1 - ms);
      const float inv = 1.f / (w0 * l_tot + w1 * l1);
      const float aw0 = w0 * inv, aw1 = w1 * inv;
      const size_t orow = (size_t)(b * 2048 + qrow) * 2048 + h * 128;
#pragma unroll
      for (int dt = 0; dt < 4; ++dt) {
        const int rbase = ((qg * 4 + dt) * 32 + l31) * 32;
#pragma unroll
        for (int m_ = 0; m_ < 4; ++m_) {
          f32x4 o1v = *(const f32x4*)&Mrg[rbase + (((hi * 4 + m_) ^ sw8) << 2)];
          u64 val = 0;
#pragma unroll
          for (int r = 0; r < 4; ++r) {
            __hip_bfloat16 hb =
                __float2bfloat16(aw0 * o[dt][4 * m_ + r] + aw1 * o1v[r]);
            val |= (u64)(*(u16*)&hb) << (16 * r);
          }
          *(u64*)&ao[orow + dt * 32 + 8 * m_ + 4 * hi] = val;
        }
      }
    }
    __syncthreads();                 // protect Mrg/Mlb before next-phase staging
  }
#undef STAGE_K
#undef STAGE_V
}

// ---------------------------------------------------------------- launch
extern "C" void kernel_launch(void* const* d_in, const int* in_sizes, int n_in,
                              void* d_out, int out_size, void* d_ws, size_t ws_size,
                              hipStream_t stream) {
  const float* x  = (const float*)d_in[0];
  const float* wq = (const float*)d_in[2];
  const float* wk = (const float*)d_in[3];
  const float* wv = (const float*)d_in[4];
  const float* wo = (const float*)d_in[5];
  float* out = (float*)d_out;

  u16* xb   = (u16*)d_ws;                       // x bf16   [4096][2048]
  u16* wqkv = xb + (size_t)8388608;             // W bf16   [3072][2048]
  u16* qkv  = wqkv + (size_t)6291456;           // qkv      [4096][3072]
  u16* vtg  = qkv + (size_t)12582912;           // V^T      [8][128][2048]
  u16* wob  = vtg + (size_t)2097152;            // wo bf16  [2048][2048]
  u16* ao   = xb;                               // attn out [4096][2048] (reuse xb)

  cast_all<<<18432, 256, 0, stream>>>(x, wq, wk, wv, wo, xb, wqkv, wob);

  gemm_sm<u16><<<dim3(24, 32), 256, 0, stream>>>(xb, wqkv, qkv, 4096, 3072, 2048);

  rope_vtrans<<<20736, 256, 0, stream>>>(qkv, vtg);

  attn_kernel<<<512, 256, 0, stream>>>(qkv, vtg, ao);

  gemm_sm<float><<<dim3(16, 32), 256, 0, stream>>>(ao, wob, out, 4096, 2048, 2048);
}